// Round 15
// baseline (637.900 us; speedup 1.0000x reference)
//
#include <hip/hip_runtime.h>
#include <hip/hip_bf16.h>

typedef __bf16 bf16x8 __attribute__((ext_vector_type(8)));
typedef float  f32x4  __attribute__((ext_vector_type(4)));

#define NB 32
#define NS 2048
#define ND 512
#define NH 512
#define NROWS (NB*NS)
#define L2E 1.44269504f

__device__ __forceinline__ void gload16(const void* g, void* l) {
  __builtin_amdgcn_global_load_lds((const __attribute__((address_space(1))) void*)g,
                                   (__attribute__((address_space(3))) void*)l, 16, 0, 0);
}

// ---------------------------------------------------------------------------
// prep: W[d][h] (f32) -> wT[m][h][d] (bf16)
// ---------------------------------------------------------------------------
__global__ void prep_w(const float* __restrict__ Wq, const float* __restrict__ Wk,
                       const float* __restrict__ Wv, __bf16* __restrict__ wT) {
  int i = blockIdx.x * blockDim.x + threadIdx.x;
  const int total = 3 * ND * NH;
  for (; i < total; i += gridDim.x * blockDim.x) {
    int m = i / (ND * NH);
    int rem = i - m * (ND * NH);
    int h = rem >> 9;
    int d = rem & 511;
    const float* W = (m == 0) ? Wq : ((m == 1) ? Wk : Wv);
    wT[i] = (__bf16)W[(size_t)d * NH + h];
  }
}

// ---------------------------------------------------------------------------
// K1: fused 3-mode projection with counted-vmcnt W pipeline (round-11/13,
// validated). 3 W bufs + x = 160KB; red arrays alias W buf m. Tail handled
// via gs<47 ? vmcnt(4) : vmcnt(0).
// ---------------------------------------------------------------------------
#define K1_XOFF 0
#define K1_WOFF 65536        // 3 x 32768
#define K1_LDS  163840

__global__ __launch_bounds__(512, 1)
void proj_kernel(const float* __restrict__ x, const __bf16* __restrict__ wT,
                 __bf16* __restrict__ p_out, __bf16* __restrict__ k_out,
                 float* __restrict__ L_out, __bf16* __restrict__ vt_out)
{
  __shared__ __align__(16) char smem[K1_LDS];
  char* xb = smem + K1_XOFF;
  char* wb = smem + K1_WOFF;

  const int tid = threadIdx.x;
  const int lane = tid & 63, l15 = lane & 15, g = lane >> 4;
  const int w = tid >> 6, rt = w & 1, cs = w >> 1;
  const int r0 = blockIdx.x * 64;
  const int b = r0 >> 11, s0 = r0 & (NS - 1);

  {
    int row = tid >> 3, sc = tid & 7;
    const float* xr = x + (size_t)(r0 + row) * ND;
    #pragma unroll
    for (int u = 0; u < 8; ++u) {
      int s = u * 8 + sc;
      float4 v0 = *(const float4*)(xr + s * 8);
      float4 v1 = *(const float4*)(xr + s * 8 + 4);
      bf16x8 cv;
      cv[0]=(__bf16)v0.x; cv[1]=(__bf16)v0.y; cv[2]=(__bf16)v0.z; cv[3]=(__bf16)v0.w;
      cv[4]=(__bf16)v1.x; cv[5]=(__bf16)v1.y; cv[6]=(__bf16)v1.z; cv[7]=(__bf16)v1.w;
      *(bf16x8*)(xb + row * 1024 + ((s ^ (row & 7)) * 16)) = cv;
    }
  }
  #define STAGEW(GS) { \
    int mn_ = (GS) >> 4, sn_ = (GS) & 15; \
    const __bf16* ws_ = wT + (size_t)mn_ * (ND * NH) + sn_ * 32; \
    char* wd_ = wb + ((GS) % 3) * 32768; \
    _Pragma("unroll") \
    for (int u_ = 0; u_ < 4; ++u_) { \
      int sid_ = u_ * 512 + tid, h_ = sid_ >> 2, gg_ = sid_ & 3; \
      gload16(ws_ + (size_t)h_ * ND + ((gg_ ^ ((h_ >> 1) & 3)) * 8), wd_ + sid_ * 16); \
    } }
  STAGEW(0);
  STAGEW(1);

  for (int m = 0; m < 3; ++m) {
    f32x4 acc[2][8];
    #pragma unroll
    for (int i2 = 0; i2 < 2; ++i2)
      #pragma unroll
      for (int ht = 0; ht < 8; ++ht) acc[i2][ht] = (f32x4){0.f,0.f,0.f,0.f};

    for (int step = 0; step < 16; ++step) {
      int gs = m * 16 + step;
      if (gs < 47) { asm volatile("s_waitcnt vmcnt(4) lgkmcnt(0)" ::: "memory"); }
      else         { asm volatile("s_waitcnt vmcnt(0) lgkmcnt(0)" ::: "memory"); }
      __builtin_amdgcn_sched_barrier(0);
      __builtin_amdgcn_s_barrier();
      __builtin_amdgcn_sched_barrier(0);
      if (gs + 2 < 48) STAGEW(gs + 2);

      const char* wcur = wb + (gs % 3) * 32768;
      bf16x8 a0, a1;
      {
        int ar = rt * 32 + l15;
        a0 = *(const bf16x8*)(xb + ar * 1024 + (((step * 4 + g) ^ (ar & 7)) * 16));
        ar += 16;
        a1 = *(const bf16x8*)(xb + ar * 1024 + (((step * 4 + g) ^ (ar & 7)) * 16));
      }
      #pragma unroll
      for (int ht = 0; ht < 8; ++ht) {
        int h = cs * 128 + ht * 16 + l15;
        bf16x8 bb = *(const bf16x8*)(wcur + h * 64 + ((g ^ ((h >> 1) & 3)) * 16));
        __builtin_amdgcn_s_setprio(1);
        acc[0][ht] = __builtin_amdgcn_mfma_f32_16x16x32_bf16(a0, bb, acc[0][ht], 0, 0, 0);
        acc[1][ht] = __builtin_amdgcn_mfma_f32_16x16x32_bf16(a1, bb, acc[1][ht], 0, 0, 0);
        __builtin_amdgcn_s_setprio(0);
      }
    }

    if (m == 2) {
      #pragma unroll
      for (int i2 = 0; i2 < 2; ++i2) {
        int sgg = (s0 >> 3) + rt * 4 + i2 * 2 + (g >> 1);
        size_t basep = ((size_t)(b * 256 + sgg)) * 512;
        #pragma unroll
        for (int ht = 0; ht < 8; ++ht) {
          int h = cs * 128 + ht * 16 + l15;
          union { __bf16 h4[4]; ushort4 u4; } cv;
          #pragma unroll
          for (int r = 0; r < 4; ++r) cv.h4[r] = (__bf16)acc[i2][ht][r];
          *(ushort4*)(vt_out + (basep + h) * 8 + (g & 1) * 4) = cv.u4;
        }
      }
    } else {
      float* redm = (float*)(wb + m * 32768);
      float* reds = redm + 256;
      asm volatile("s_waitcnt lgkmcnt(0)" ::: "memory");
      __builtin_amdgcn_sched_barrier(0);
      __builtin_amdgcn_s_barrier();
      __builtin_amdgcn_sched_barrier(0);

      float mrow[2][4], tsum[2][4];
      #pragma unroll
      for (int i2 = 0; i2 < 2; ++i2)
        #pragma unroll
        for (int r = 0; r < 4; ++r) {
          float v = acc[i2][0][r];
          #pragma unroll
          for (int ht = 1; ht < 8; ++ht) v = fmaxf(v, acc[i2][ht][r]);
          v = fmaxf(v, __shfl_xor(v, 1)); v = fmaxf(v, __shfl_xor(v, 2));
          v = fmaxf(v, __shfl_xor(v, 4)); v = fmaxf(v, __shfl_xor(v, 8));
          if (l15 == 0) redm[cs * 64 + rt * 32 + i2 * 16 + g * 4 + r] = v;
        }
      asm volatile("s_waitcnt lgkmcnt(0)" ::: "memory");
      __builtin_amdgcn_s_barrier();
      #pragma unroll
      for (int i2 = 0; i2 < 2; ++i2)
        #pragma unroll
        for (int r = 0; r < 4; ++r) {
          int row = rt * 32 + i2 * 16 + g * 4 + r;
          mrow[i2][r] = fmaxf(fmaxf(redm[row], redm[64 + row]),
                              fmaxf(redm[128 + row], redm[192 + row]));
        }
      #pragma unroll
      for (int i2 = 0; i2 < 2; ++i2)
        #pragma unroll
        for (int r = 0; r < 4; ++r) {
          float s = 0.f;
          #pragma unroll
          for (int ht = 0; ht < 8; ++ht) s += exp2f((acc[i2][ht][r] - mrow[i2][r]) * L2E);
          s += __shfl_xor(s, 1); s += __shfl_xor(s, 2);
          s += __shfl_xor(s, 4); s += __shfl_xor(s, 8);
          if (l15 == 0) reds[cs * 64 + rt * 32 + i2 * 16 + g * 4 + r] = s;
        }
      asm volatile("s_waitcnt lgkmcnt(0)" ::: "memory");
      __builtin_amdgcn_s_barrier();
      #pragma unroll
      for (int i2 = 0; i2 < 2; ++i2)
        #pragma unroll
        for (int r = 0; r < 4; ++r) {
          int row = rt * 32 + i2 * 16 + g * 4 + r;
          tsum[i2][r] = reds[row] + reds[64 + row] + reds[128 + row] + reds[192 + row];
        }
      __bf16* dst = (m == 0) ? p_out : k_out;
      if (m == 0) {
        #pragma unroll
        for (int i2 = 0; i2 < 2; ++i2) {
          float inv[4];
          #pragma unroll
          for (int r = 0; r < 4; ++r) inv[r] = 1.f / tsum[i2][r];
          #pragma unroll
          for (int ht = 0; ht < 8; ++ht) {
            int col = cs * 128 + ht * 16 + l15;
            #pragma unroll
            for (int r = 0; r < 4; ++r) {
              int row = rt * 32 + i2 * 16 + g * 4 + r;
              dst[(size_t)(r0 + row) * NH + col] =
                  (__bf16)(exp2f((acc[i2][ht][r] - mrow[i2][r]) * L2E) * inv[r]);
            }
          }
        }
      } else {
        #pragma unroll
        for (int i2 = 0; i2 < 2; ++i2)
          #pragma unroll
          for (int ht = 0; ht < 8; ++ht) {
            int col = cs * 128 + ht * 16 + l15;
            #pragma unroll
            for (int r = 0; r < 4; ++r) {
              int row = rt * 32 + i2 * 16 + g * 4 + r;
              dst[(size_t)(r0 + row) * NH + col] = (__bf16)acc[i2][ht][r];
            }
          }
        if (cs == 0 && l15 == 0) {
          #pragma unroll
          for (int i2 = 0; i2 < 2; ++i2)
            #pragma unroll
            for (int r = 0; r < 4; ++r) {
              int row = rt * 32 + i2 * 16 + g * 4 + r;
              L_out[r0 + row] = mrow[i2][r] + __logf(tsum[i2][r]);
            }
        }
      }
      asm volatile("s_waitcnt lgkmcnt(0)" ::: "memory");
      __builtin_amdgcn_s_barrier();
    }
  }
}

// ---------------------------------------------------------------------------
// K2: round-7/13 fused attention + ss==63 TAIL FIX: at the last outer's kk7,
// only stage 63's own 4 loads are outstanding, so vmcnt(4) never certified
// it (latent race, flaky at replay). vmcnt(0) there closes it; all other
// steps keep the counted vmcnt(4).
// ---------------------------------------------------------------------------
#define QOFF 0
#define KOFF 65536
#define PSTR 512
#define A_LDS 163840

__global__ __launch_bounds__(512, 2)
void attn_kernel(const __bf16* __restrict__ p_all, const __bf16* __restrict__ k_all,
                 const float* __restrict__ L_all, const __bf16* __restrict__ vt_all,
                 float* __restrict__ out)
{
  __shared__ __align__(16) char smem[A_LDS];
  char* Qb = smem + QOFF;
  float* lred = (float*)(smem + KOFF);   // used only after final barrier

  const int bid = blockIdx.x;
  const int b = ((bid >> 8) << 3) + (bid & 7);   // batch-grouped XCD swizzle
  const int ib = (bid >> 3) & 31;
  const int i0 = ib * 64;

  const __bf16* Pg = p_all + (size_t)b * NS * NH;
  const __bf16* Kg = k_all + (size_t)b * NS * NH;
  const float*  Lg = L_all + (size_t)b * NS;
  const __bf16* Vg = vt_all + (size_t)b * (256 * 512 * 8);
  float* Og = out + ((size_t)b * NS + i0) * NH;

  const int tid = threadIdx.x;
  const int lane = tid & 63, l15 = lane & 15, g = lane >> 4;
  const int w = tid >> 6;
  const int ig = w >> 2, jg = w & 3;   // scores roles
  const int hs = w * 64;               // PV role
  const int xr = l15 & 7;

  #define STAGE(SS) { \
    int j0_ = ((SS) >> 3) * 256, kh_ = (SS) & 7; \
    char* kd_ = smem + KOFF + ((SS) % 3) * 32768; \
    _Pragma("unroll") \
    for (int u_ = 0; u_ < 4; ++u_) { \
      int sid_ = u_ * 512 + tid, jj_ = sid_ >> 3, s8_ = sid_ & 7; \
      gload16(Kg + (size_t)(j0_ + jj_) * NH + kh_ * 64 + ((s8_ ^ (jj_ & 7)) * 8), \
              kd_ + sid_ * 16); \
    } }

  // ---- prologue: Q -> LDS (source-XOR), stages 0 and 1 ----
  #pragma unroll
  for (int u = 0; u < 8; ++u) {
    int sid = u * 512 + tid, row = sid >> 6, s = sid & 63;
    int sp = (s & 56) | ((s ^ row) & 7);
    gload16(Pg + (size_t)(i0 + row) * NH + sp * 8, Qb + sid * 16);
  }
  STAGE(0);
  STAGE(1);
  // first kk-step's vmcnt(4)+barrier certifies Q and stage 0

  f32x4 o_[4][4];
  #pragma unroll
  for (int it = 0; it < 4; ++it)
    #pragma unroll
    for (int ht = 0; ht < 4; ++ht) o_[it][ht] = (f32x4){0.f,0.f,0.f,0.f};
  float lsum[2][4] = {{0.f,0.f,0.f,0.f},{0.f,0.f,0.f,0.f}};

  #define LOADV(DST, KS) { \
    _Pragma("unroll") \
    for (int ht_ = 0; ht_ < 4; ++ht_) { \
      int h_ = hs + ht_ * 16 + l15; \
      int sg_ = outer * 32 + (KS) * 4 + g; \
      (DST)[ht_] = *(const bf16x8*)(Vg + ((size_t)sg_ * 512 + h_) * 8); \
    } }
  #define PVSTEP(KS, VF) { \
    __builtin_amdgcn_s_setprio(1); \
    _Pragma("unroll") \
    for (int it_ = 0; it_ < 4; ++it_) { \
      bf16x8 pa_ = *(const bf16x8*)(Pb + (it_ * 16 + l15) * PSTR + (((KS) * 4 + g) ^ xr) * 16); \
      _Pragma("unroll") \
      for (int ht_ = 0; ht_ < 4; ++ht_) \
        o_[it_][ht_] = __builtin_amdgcn_mfma_f32_16x16x32_bf16(pa_, (VF)[ht_], o_[it_][ht_], 0, 0, 0); \
    } \
    __builtin_amdgcn_s_setprio(0); }

  for (int outer = 0; outer < 8; ++outer) {
    const int j0 = outer * 256;
    f32x4 acc[2][4];
    #pragma unroll
    for (int i2 = 0; i2 < 2; ++i2)
      #pragma unroll
      for (int jt = 0; jt < 4; ++jt) acc[i2][jt] = (f32x4){0.f,0.f,0.f,0.f};

    #pragma unroll
    for (int kk = 0; kk < 8; ++kk) {
      const int ss = outer * 8 + kk;
      // certify stage ss. ss<63: next stage(s) in flight -> counted vmcnt(4).
      // ss==63: ONLY stage 63's own loads outstanding -> vmcnt(0) (tail fix).
      if (ss < 63) { asm volatile("s_waitcnt vmcnt(4)" ::: "memory"); }
      else         { asm volatile("s_waitcnt vmcnt(0)" ::: "memory"); }
      __builtin_amdgcn_sched_barrier(0);
      __builtin_amdgcn_s_barrier();
      __builtin_amdgcn_sched_barrier(0);
      if (ss + 2 < 64) STAGE(ss + 2);
      const char* rb = smem + KOFF + (ss % 3) * 32768;
      #pragma unroll
      for (int sub = 0; sub < 2; ++sub) {
        bf16x8 a0, a1, bq[4];
        {
          int row0 = ig * 32 + l15;
          int seg = kk * 8 + sub * 4 + g;
          a0 = *(const bf16x8*)(Qb + row0 * 1024 + ((seg ^ (row0 & 7)) * 16));
          a1 = *(const bf16x8*)(Qb + (row0 + 16) * 1024 + ((seg ^ ((row0 + 16) & 7)) * 16));
        }
        #pragma unroll
        for (int jt = 0; jt < 4; ++jt) {
          int j = jg * 64 + jt * 16 + l15;
          bq[jt] = *(const bf16x8*)(rb + j * 128 + (((sub * 4 + g) ^ xr) * 16));
        }
        __builtin_amdgcn_s_setprio(1);
        #pragma unroll
        for (int jt = 0; jt < 4; ++jt) {
          acc[0][jt] = __builtin_amdgcn_mfma_f32_16x16x32_bf16(a0, bq[jt], acc[0][jt], 0, 0, 0);
          acc[1][jt] = __builtin_amdgcn_mfma_f32_16x16x32_bf16(a1, bq[jt], acc[1][jt], 0, 0, 0);
        }
        __builtin_amdgcn_s_setprio(0);
      }
    }

    // K buffer (8*outer+7)%3 consumed by all waves after this barrier -> P home
    __builtin_amdgcn_sched_barrier(0);
    __builtin_amdgcn_s_barrier();
    __builtin_amdgcn_sched_barrier(0);
    char* Pb = smem + KOFF + ((outer * 8 + 7) % 3) * 32768;

    // ---- epilogue: weights + P write (swizzled) ----
    {
      float LB[4];
      #pragma unroll
      for (int jt = 0; jt < 4; ++jt) LB[jt] = Lg[j0 + jg * 64 + jt * 16 + l15] * L2E;
      #pragma unroll
      for (int i2 = 0; i2 < 2; ++i2)
        #pragma unroll
        for (int jt = 0; jt < 4; ++jt)
          #pragma unroll
          for (int r = 0; r < 4; ++r) {
            float pv = exp2f(acc[i2][jt][r] * L2E - LB[jt]);
            lsum[i2][r] += pv;
            float other = __shfl_xor(pv, 1);
            if ((l15 & 1) == 0) {
              union { __bf16 h; unsigned short u; } lo, hi;
              lo.h = (__bf16)pv; hi.h = (__bf16)other;
              unsigned int pk = (unsigned int)lo.u | ((unsigned int)hi.u << 16);
              int row = ig * 32 + i2 * 16 + g * 4 + r;
              int d = jg * 32 + jt * 8 + (l15 >> 1);
              int s2 = (d >> 2) ^ (row & 7);
              *(unsigned int*)(Pb + row * PSTR + s2 * 16 + (d & 3) * 4) = pk;
            }
          }
    }
    // V pre-loads hide under the P barrier
    bf16x8 vA[4], vB[4];
    LOADV(vA, 0); LOADV(vB, 1);
    asm volatile("s_waitcnt lgkmcnt(0)" ::: "memory");
    __builtin_amdgcn_sched_barrier(0);
    __builtin_amdgcn_s_barrier();
    __builtin_amdgcn_sched_barrier(0);

    // ---- PV: 2-deep V rotation ----
    PVSTEP(0, vA); LOADV(vA, 2);
    PVSTEP(1, vB); LOADV(vB, 3);
    PVSTEP(2, vA); LOADV(vA, 4);
    PVSTEP(3, vB); LOADV(vB, 5);
    PVSTEP(4, vA); LOADV(vA, 6);
    PVSTEP(5, vB); LOADV(vB, 7);
    PVSTEP(6, vA);
    PVSTEP(7, vB);
    // next outer's first vmcnt+barrier separates PV P-reads from new staging
  }

  // ---- lsum reduce across l15, then across jg waves via LDS (K buf 0) ----
  __syncthreads();
  #pragma unroll
  for (int i2 = 0; i2 < 2; ++i2)
    #pragma unroll
    for (int r = 0; r < 4; ++r) {
      float v = lsum[i2][r];
      v += __shfl_xor(v, 1); v += __shfl_xor(v, 2);
      v += __shfl_xor(v, 4); v += __shfl_xor(v, 8);
      if (l15 == 0) lred[jg * 64 + ig * 32 + i2 * 16 + g * 4 + r] = v;
    }
  __syncthreads();

  #pragma unroll
  for (int it = 0; it < 4; ++it) {
    float inv[4];
    #pragma unroll
    for (int r = 0; r < 4; ++r) {
      int row = it * 16 + g * 4 + r;
      inv[r] = 1.f / (lred[row] + lred[64 + row] + lred[128 + row] + lred[192 + row]);
    }
    #pragma unroll
    for (int ht = 0; ht < 4; ++ht)
      #pragma unroll
      for (int r = 0; r < 4; ++r) {
        int row = it * 16 + g * 4 + r;
        Og[(size_t)row * NH + hs + ht * 16 + l15] = o_[it][ht][r] * inv[r];
      }
  }
}

// ---------------------------------------------------------------------------
extern "C" void kernel_launch(void* const* d_in, const int* in_sizes, int n_in,
                              void* d_out, int out_size, void* d_ws, size_t ws_size,
                              hipStream_t stream) {
  const float* x  = (const float*)d_in[0];
  const float* Wq = (const float*)d_in[1];
  const float* Wk = (const float*)d_in[2];
  const float* Wv = (const float*)d_in[3];
  float* out = (float*)d_out;
  char* ws = (char*)d_ws;

  size_t off = 0;
  __bf16* wT   = (__bf16*)(ws + off); off += (size_t)3 * ND * NH * 2;   // 1.5 MB
  __bf16* p_ws = (__bf16*)(ws + off); off += (size_t)NROWS * NH * 2;    // 64 MB
  __bf16* k_ws = (__bf16*)(ws + off); off += (size_t)NROWS * NH * 2;    // 64 MB
  __bf16* vt_ws= (__bf16*)(ws + off); off += (size_t)NROWS * NH * 2;    // 64 MB (tiled)
  float*  L_ws = (float*)(ws + off);  off += (size_t)NROWS * 4;         // 0.25 MB

  prep_w<<<dim3(512), dim3(256), 0, stream>>>(Wq, Wk, Wv, wT);
  proj_kernel<<<dim3(1024), dim3(512), 0, stream>>>(x, wT, p_ws, k_ws, L_ws, vt_ws);
  attn_kernel<<<dim3(1024), dim3(512), 0, stream>>>(p_ws, k_ws, L_ws, vt_ws, out);
}

// Round 16
// 632.285 us; speedup vs baseline: 1.0089x; 1.0089x over previous
//
#include <hip/hip_runtime.h>
#include <hip/hip_bf16.h>

typedef __bf16 bf16x8 __attribute__((ext_vector_type(8)));
typedef float  f32x4  __attribute__((ext_vector_type(4)));

#define NB 32
#define NS 2048
#define ND 512
#define NH 512
#define NROWS (NB*NS)
#define L2E 1.44269504f

__device__ __forceinline__ void gload16(const void* g, void* l) {
  __builtin_amdgcn_global_load_lds((const __attribute__((address_space(1))) void*)g,
                                   (__attribute__((address_space(3))) void*)l, 16, 0, 0);
}

// ---------------------------------------------------------------------------
// prep: W[d][h] (f32) -> wT[m][h][d] (bf16)
// ---------------------------------------------------------------------------
__global__ void prep_w(const float* __restrict__ Wq, const float* __restrict__ Wk,
                       const float* __restrict__ Wv, __bf16* __restrict__ wT) {
  int i = blockIdx.x * blockDim.x + threadIdx.x;
  const int total = 3 * ND * NH;
  for (; i < total; i += gridDim.x * blockDim.x) {
    int m = i / (ND * NH);
    int rem = i - m * (ND * NH);
    int h = rem >> 9;
    int d = rem & 511;
    const float* W = (m == 0) ? Wq : ((m == 1) ? Wk : Wv);
    wT[i] = (__bf16)W[(size_t)d * NH + h];
  }
}

// ---------------------------------------------------------------------------
// K1: fused 3-mode projection with counted-vmcnt W pipeline (round-13/15,
// validated). 3 W bufs + x = 160KB; red arrays alias W buf m. Tail handled
// via gs<47 ? vmcnt(4) : vmcnt(0).
// Round-16: setprio hoisted to ONE pair around the 16-MFMA cluster
// (semantically inert priority hint; r14's failure was the attn tail race,
// fixed in r15).
// ---------------------------------------------------------------------------
#define K1_XOFF 0
#define K1_WOFF 65536        // 3 x 32768
#define K1_LDS  163840

__global__ __launch_bounds__(512, 1)
void proj_kernel(const float* __restrict__ x, const __bf16* __restrict__ wT,
                 __bf16* __restrict__ p_out, __bf16* __restrict__ k_out,
                 float* __restrict__ L_out, __bf16* __restrict__ vt_out)
{
  __shared__ __align__(16) char smem[K1_LDS];
  char* xb = smem + K1_XOFF;
  char* wb = smem + K1_WOFF;

  const int tid = threadIdx.x;
  const int lane = tid & 63, l15 = lane & 15, g = lane >> 4;
  const int w = tid >> 6, rt = w & 1, cs = w >> 1;
  const int r0 = blockIdx.x * 64;
  const int b = r0 >> 11, s0 = r0 & (NS - 1);

  {
    int row = tid >> 3, sc = tid & 7;
    const float* xr = x + (size_t)(r0 + row) * ND;
    #pragma unroll
    for (int u = 0; u < 8; ++u) {
      int s = u * 8 + sc;
      float4 v0 = *(const float4*)(xr + s * 8);
      float4 v1 = *(const float4*)(xr + s * 8 + 4);
      bf16x8 cv;
      cv[0]=(__bf16)v0.x; cv[1]=(__bf16)v0.y; cv[2]=(__bf16)v0.z; cv[3]=(__bf16)v0.w;
      cv[4]=(__bf16)v1.x; cv[5]=(__bf16)v1.y; cv[6]=(__bf16)v1.z; cv[7]=(__bf16)v1.w;
      *(bf16x8*)(xb + row * 1024 + ((s ^ (row & 7)) * 16)) = cv;
    }
  }
  #define STAGEW(GS) { \
    int mn_ = (GS) >> 4, sn_ = (GS) & 15; \
    const __bf16* ws_ = wT + (size_t)mn_ * (ND * NH) + sn_ * 32; \
    char* wd_ = wb + ((GS) % 3) * 32768; \
    _Pragma("unroll") \
    for (int u_ = 0; u_ < 4; ++u_) { \
      int sid_ = u_ * 512 + tid, h_ = sid_ >> 2, gg_ = sid_ & 3; \
      gload16(ws_ + (size_t)h_ * ND + ((gg_ ^ ((h_ >> 1) & 3)) * 8), wd_ + sid_ * 16); \
    } }
  STAGEW(0);
  STAGEW(1);

  for (int m = 0; m < 3; ++m) {
    f32x4 acc[2][8];
    #pragma unroll
    for (int i2 = 0; i2 < 2; ++i2)
      #pragma unroll
      for (int ht = 0; ht < 8; ++ht) acc[i2][ht] = (f32x4){0.f,0.f,0.f,0.f};

    for (int step = 0; step < 16; ++step) {
      int gs = m * 16 + step;
      if (gs < 47) { asm volatile("s_waitcnt vmcnt(4) lgkmcnt(0)" ::: "memory"); }
      else         { asm volatile("s_waitcnt vmcnt(0) lgkmcnt(0)" ::: "memory"); }
      __builtin_amdgcn_sched_barrier(0);
      __builtin_amdgcn_s_barrier();
      __builtin_amdgcn_sched_barrier(0);
      if (gs + 2 < 48) STAGEW(gs + 2);

      const char* wcur = wb + (gs % 3) * 32768;
      bf16x8 a0, a1;
      {
        int ar = rt * 32 + l15;
        a0 = *(const bf16x8*)(xb + ar * 1024 + (((step * 4 + g) ^ (ar & 7)) * 16));
        ar += 16;
        a1 = *(const bf16x8*)(xb + ar * 1024 + (((step * 4 + g) ^ (ar & 7)) * 16));
      }
      __builtin_amdgcn_s_setprio(1);
      #pragma unroll
      for (int ht = 0; ht < 8; ++ht) {
        int h = cs * 128 + ht * 16 + l15;
        bf16x8 bb = *(const bf16x8*)(wcur + h * 64 + ((g ^ ((h >> 1) & 3)) * 16));
        acc[0][ht] = __builtin_amdgcn_mfma_f32_16x16x32_bf16(a0, bb, acc[0][ht], 0, 0, 0);
        acc[1][ht] = __builtin_amdgcn_mfma_f32_16x16x32_bf16(a1, bb, acc[1][ht], 0, 0, 0);
      }
      __builtin_amdgcn_s_setprio(0);
    }

    if (m == 2) {
      #pragma unroll
      for (int i2 = 0; i2 < 2; ++i2) {
        int sgg = (s0 >> 3) + rt * 4 + i2 * 2 + (g >> 1);
        size_t basep = ((size_t)(b * 256 + sgg)) * 512;
        #pragma unroll
        for (int ht = 0; ht < 8; ++ht) {
          int h = cs * 128 + ht * 16 + l15;
          union { __bf16 h4[4]; ushort4 u4; } cv;
          #pragma unroll
          for (int r = 0; r < 4; ++r) cv.h4[r] = (__bf16)acc[i2][ht][r];
          *(ushort4*)(vt_out + (basep + h) * 8 + (g & 1) * 4) = cv.u4;
        }
      }
    } else {
      float* redm = (float*)(wb + m * 32768);
      float* reds = redm + 256;
      asm volatile("s_waitcnt lgkmcnt(0)" ::: "memory");
      __builtin_amdgcn_sched_barrier(0);
      __builtin_amdgcn_s_barrier();
      __builtin_amdgcn_sched_barrier(0);

      float mrow[2][4], tsum[2][4];
      #pragma unroll
      for (int i2 = 0; i2 < 2; ++i2)
        #pragma unroll
        for (int r = 0; r < 4; ++r) {
          float v = acc[i2][0][r];
          #pragma unroll
          for (int ht = 1; ht < 8; ++ht) v = fmaxf(v, acc[i2][ht][r]);
          v = fmaxf(v, __shfl_xor(v, 1)); v = fmaxf(v, __shfl_xor(v, 2));
          v = fmaxf(v, __shfl_xor(v, 4)); v = fmaxf(v, __shfl_xor(v, 8));
          if (l15 == 0) redm[cs * 64 + rt * 32 + i2 * 16 + g * 4 + r] = v;
        }
      asm volatile("s_waitcnt lgkmcnt(0)" ::: "memory");
      __builtin_amdgcn_s_barrier();
      #pragma unroll
      for (int i2 = 0; i2 < 2; ++i2)
        #pragma unroll
        for (int r = 0; r < 4; ++r) {
          int row = rt * 32 + i2 * 16 + g * 4 + r;
          mrow[i2][r] = fmaxf(fmaxf(redm[row], redm[64 + row]),
                              fmaxf(redm[128 + row], redm[192 + row]));
        }
      #pragma unroll
      for (int i2 = 0; i2 < 2; ++i2)
        #pragma unroll
        for (int r = 0; r < 4; ++r) {
          float s = 0.f;
          #pragma unroll
          for (int ht = 0; ht < 8; ++ht) s += exp2f((acc[i2][ht][r] - mrow[i2][r]) * L2E);
          s += __shfl_xor(s, 1); s += __shfl_xor(s, 2);
          s += __shfl_xor(s, 4); s += __shfl_xor(s, 8);
          if (l15 == 0) reds[cs * 64 + rt * 32 + i2 * 16 + g * 4 + r] = s;
        }
      asm volatile("s_waitcnt lgkmcnt(0)" ::: "memory");
      __builtin_amdgcn_s_barrier();
      #pragma unroll
      for (int i2 = 0; i2 < 2; ++i2)
        #pragma unroll
        for (int r = 0; r < 4; ++r) {
          int row = rt * 32 + i2 * 16 + g * 4 + r;
          tsum[i2][r] = reds[row] + reds[64 + row] + reds[128 + row] + reds[192 + row];
        }
      __bf16* dst = (m == 0) ? p_out : k_out;
      if (m == 0) {
        #pragma unroll
        for (int i2 = 0; i2 < 2; ++i2) {
          float inv[4];
          #pragma unroll
          for (int r = 0; r < 4; ++r) inv[r] = 1.f / tsum[i2][r];
          #pragma unroll
          for (int ht = 0; ht < 8; ++ht) {
            int col = cs * 128 + ht * 16 + l15;
            #pragma unroll
            for (int r = 0; r < 4; ++r) {
              int row = rt * 32 + i2 * 16 + g * 4 + r;
              dst[(size_t)(r0 + row) * NH + col] =
                  (__bf16)(exp2f((acc[i2][ht][r] - mrow[i2][r]) * L2E) * inv[r]);
            }
          }
        }
      } else {
        #pragma unroll
        for (int i2 = 0; i2 < 2; ++i2)
          #pragma unroll
          for (int ht = 0; ht < 8; ++ht) {
            int col = cs * 128 + ht * 16 + l15;
            #pragma unroll
            for (int r = 0; r < 4; ++r) {
              int row = rt * 32 + i2 * 16 + g * 4 + r;
              dst[(size_t)(r0 + row) * NH + col] = (__bf16)acc[i2][ht][r];
            }
          }
        if (cs == 0 && l15 == 0) {
          #pragma unroll
          for (int i2 = 0; i2 < 2; ++i2)
            #pragma unroll
            for (int r = 0; r < 4; ++r) {
              int row = rt * 32 + i2 * 16 + g * 4 + r;
              L_out[r0 + row] = mrow[i2][r] + __logf(tsum[i2][r]);
            }
        }
      }
      asm volatile("s_waitcnt lgkmcnt(0)" ::: "memory");
      __builtin_amdgcn_s_barrier();
    }
  }
}

// ---------------------------------------------------------------------------
// K2: round-15 fused attention VERBATIM (tail-fixed, validated 637.9us).
// ---------------------------------------------------------------------------
#define QOFF 0
#define KOFF 65536
#define PSTR 512
#define A_LDS 163840

__global__ __launch_bounds__(512, 2)
void attn_kernel(const __bf16* __restrict__ p_all, const __bf16* __restrict__ k_all,
                 const float* __restrict__ L_all, const __bf16* __restrict__ vt_all,
                 float* __restrict__ out)
{
  __shared__ __align__(16) char smem[A_LDS];
  char* Qb = smem + QOFF;
  float* lred = (float*)(smem + KOFF);   // used only after final barrier

  const int bid = blockIdx.x;
  const int b = ((bid >> 8) << 3) + (bid & 7);   // batch-grouped XCD swizzle
  const int ib = (bid >> 3) & 31;
  const int i0 = ib * 64;

  const __bf16* Pg = p_all + (size_t)b * NS * NH;
  const __bf16* Kg = k_all + (size_t)b * NS * NH;
  const float*  Lg = L_all + (size_t)b * NS;
  const __bf16* Vg = vt_all + (size_t)b * (256 * 512 * 8);
  float* Og = out + ((size_t)b * NS + i0) * NH;

  const int tid = threadIdx.x;
  const int lane = tid & 63, l15 = lane & 15, g = lane >> 4;
  const int w = tid >> 6;
  const int ig = w >> 2, jg = w & 3;   // scores roles
  const int hs = w * 64;               // PV role
  const int xr = l15 & 7;

  #define STAGE(SS) { \
    int j0_ = ((SS) >> 3) * 256, kh_ = (SS) & 7; \
    char* kd_ = smem + KOFF + ((SS) % 3) * 32768; \
    _Pragma("unroll") \
    for (int u_ = 0; u_ < 4; ++u_) { \
      int sid_ = u_ * 512 + tid, jj_ = sid_ >> 3, s8_ = sid_ & 7; \
      gload16(Kg + (size_t)(j0_ + jj_) * NH + kh_ * 64 + ((s8_ ^ (jj_ & 7)) * 8), \
              kd_ + sid_ * 16); \
    } }

  // ---- prologue: Q -> LDS (source-XOR), stages 0 and 1 ----
  #pragma unroll
  for (int u = 0; u < 8; ++u) {
    int sid = u * 512 + tid, row = sid >> 6, s = sid & 63;
    int sp = (s & 56) | ((s ^ row) & 7);
    gload16(Pg + (size_t)(i0 + row) * NH + sp * 8, Qb + sid * 16);
  }
  STAGE(0);
  STAGE(1);
  // first kk-step's vmcnt(4)+barrier certifies Q and stage 0

  f32x4 o_[4][4];
  #pragma unroll
  for (int it = 0; it < 4; ++it)
    #pragma unroll
    for (int ht = 0; ht < 4; ++ht) o_[it][ht] = (f32x4){0.f,0.f,0.f,0.f};
  float lsum[2][4] = {{0.f,0.f,0.f,0.f},{0.f,0.f,0.f,0.f}};

  #define LOADV(DST, KS) { \
    _Pragma("unroll") \
    for (int ht_ = 0; ht_ < 4; ++ht_) { \
      int h_ = hs + ht_ * 16 + l15; \
      int sg_ = outer * 32 + (KS) * 4 + g; \
      (DST)[ht_] = *(const bf16x8*)(Vg + ((size_t)sg_ * 512 + h_) * 8); \
    } }
  #define PVSTEP(KS, VF) { \
    __builtin_amdgcn_s_setprio(1); \
    _Pragma("unroll") \
    for (int it_ = 0; it_ < 4; ++it_) { \
      bf16x8 pa_ = *(const bf16x8*)(Pb + (it_ * 16 + l15) * PSTR + (((KS) * 4 + g) ^ xr) * 16); \
      _Pragma("unroll") \
      for (int ht_ = 0; ht_ < 4; ++ht_) \
        o_[it_][ht_] = __builtin_amdgcn_mfma_f32_16x16x32_bf16(pa_, (VF)[ht_], o_[it_][ht_], 0, 0, 0); \
    } \
    __builtin_amdgcn_s_setprio(0); }

  for (int outer = 0; outer < 8; ++outer) {
    const int j0 = outer * 256;
    f32x4 acc[2][4];
    #pragma unroll
    for (int i2 = 0; i2 < 2; ++i2)
      #pragma unroll
      for (int jt = 0; jt < 4; ++jt) acc[i2][jt] = (f32x4){0.f,0.f,0.f,0.f};

    #pragma unroll
    for (int kk = 0; kk < 8; ++kk) {
      const int ss = outer * 8 + kk;
      // certify stage ss. ss<63: next stage(s) in flight -> counted vmcnt(4).
      // ss==63: ONLY stage 63's own loads outstanding -> vmcnt(0) (tail fix).
      if (ss < 63) { asm volatile("s_waitcnt vmcnt(4)" ::: "memory"); }
      else         { asm volatile("s_waitcnt vmcnt(0)" ::: "memory"); }
      __builtin_amdgcn_sched_barrier(0);
      __builtin_amdgcn_s_barrier();
      __builtin_amdgcn_sched_barrier(0);
      if (ss + 2 < 64) STAGE(ss + 2);
      const char* rb = smem + KOFF + (ss % 3) * 32768;
      #pragma unroll
      for (int sub = 0; sub < 2; ++sub) {
        bf16x8 a0, a1, bq[4];
        {
          int row0 = ig * 32 + l15;
          int seg = kk * 8 + sub * 4 + g;
          a0 = *(const bf16x8*)(Qb + row0 * 1024 + ((seg ^ (row0 & 7)) * 16));
          a1 = *(const bf16x8*)(Qb + (row0 + 16) * 1024 + ((seg ^ ((row0 + 16) & 7)) * 16));
        }
        #pragma unroll
        for (int jt = 0; jt < 4; ++jt) {
          int j = jg * 64 + jt * 16 + l15;
          bq[jt] = *(const bf16x8*)(rb + j * 128 + (((sub * 4 + g) ^ xr) * 16));
        }
        __builtin_amdgcn_s_setprio(1);
        #pragma unroll
        for (int jt = 0; jt < 4; ++jt) {
          acc[0][jt] = __builtin_amdgcn_mfma_f32_16x16x32_bf16(a0, bq[jt], acc[0][jt], 0, 0, 0);
          acc[1][jt] = __builtin_amdgcn_mfma_f32_16x16x32_bf16(a1, bq[jt], acc[1][jt], 0, 0, 0);
        }
        __builtin_amdgcn_s_setprio(0);
      }
    }

    // K buffer (8*outer+7)%3 consumed by all waves after this barrier -> P home
    __builtin_amdgcn_sched_barrier(0);
    __builtin_amdgcn_s_barrier();
    __builtin_amdgcn_sched_barrier(0);
    char* Pb = smem + KOFF + ((outer * 8 + 7) % 3) * 32768;

    // ---- epilogue: weights + P write (swizzled) ----
    {
      float LB[4];
      #pragma unroll
      for (int jt = 0; jt < 4; ++jt) LB[jt] = Lg[j0 + jg * 64 + jt * 16 + l15] * L2E;
      #pragma unroll
      for (int i2 = 0; i2 < 2; ++i2)
        #pragma unroll
        for (int jt = 0; jt < 4; ++jt)
          #pragma unroll
          for (int r = 0; r < 4; ++r) {
            float pv = exp2f(acc[i2][jt][r] * L2E - LB[jt]);
            lsum[i2][r] += pv;
            float other = __shfl_xor(pv, 1);
            if ((l15 & 1) == 0) {
              union { __bf16 h; unsigned short u; } lo, hi;
              lo.h = (__bf16)pv; hi.h = (__bf16)other;
              unsigned int pk = (unsigned int)lo.u | ((unsigned int)hi.u << 16);
              int row = ig * 32 + i2 * 16 + g * 4 + r;
              int d = jg * 32 + jt * 8 + (l15 >> 1);
              int s2 = (d >> 2) ^ (row & 7);
              *(unsigned int*)(Pb + row * PSTR + s2 * 16 + (d & 3) * 4) = pk;
            }
          }
    }
    // V pre-loads hide under the P barrier
    bf16x8 vA[4], vB[4];
    LOADV(vA, 0); LOADV(vB, 1);
    asm volatile("s_waitcnt lgkmcnt(0)" ::: "memory");
    __builtin_amdgcn_sched_barrier(0);
    __builtin_amdgcn_s_barrier();
    __builtin_amdgcn_sched_barrier(0);

    // ---- PV: 2-deep V rotation ----
    PVSTEP(0, vA); LOADV(vA, 2);
    PVSTEP(1, vB); LOADV(vB, 3);
    PVSTEP(2, vA); LOADV(vA, 4);
    PVSTEP(3, vB); LOADV(vB, 5);
    PVSTEP(4, vA); LOADV(vA, 6);
    PVSTEP(5, vB); LOADV(vB, 7);
    PVSTEP(6, vA);
    PVSTEP(7, vB);
    // next outer's first vmcnt+barrier separates PV P-reads from new staging
  }

  // ---- lsum reduce across l15, then across jg waves via LDS (K buf 0) ----
  __syncthreads();
  #pragma unroll
  for (int i2 = 0; i2 < 2; ++i2)
    #pragma unroll
    for (int r = 0; r < 4; ++r) {
      float v = lsum[i2][r];
      v += __shfl_xor(v, 1); v += __shfl_xor(v, 2);
      v += __shfl_xor(v, 4); v += __shfl_xor(v, 8);
      if (l15 == 0) lred[jg * 64 + ig * 32 + i2 * 16 + g * 4 + r] = v;
    }
  __syncthreads();

  #pragma unroll
  for (int it = 0; it < 4; ++it) {
    float inv[4];
    #pragma unroll
    for (int r = 0; r < 4; ++r) {
      int row = it * 16 + g * 4 + r;
      inv[r] = 1.f / (lred[row] + lred[64 + row] + lred[128 + row] + lred[192 + row]);
    }
    #pragma unroll
    for (int ht = 0; ht < 4; ++ht)
      #pragma unroll
      for (int r = 0; r < 4; ++r) {
        int row = it * 16 + g * 4 + r;
        Og[(size_t)row * NH + hs + ht * 16 + l15] = o_[it][ht][r] * inv[r];
      }
  }
}

// ---------------------------------------------------------------------------
extern "C" void kernel_launch(void* const* d_in, const int* in_sizes, int n_in,
                              void* d_out, int out_size, void* d_ws, size_t ws_size,
                              hipStream_t stream) {
  const float* x  = (const float*)d_in[0];
  const float* Wq = (const float*)d_in[1];
  const float* Wk = (const float*)d_in[2];
  const float* Wv = (const float*)d_in[3];
  float* out = (float*)d_out;
  char* ws = (char*)d_ws;

  size_t off = 0;
  __bf16* wT   = (__bf16*)(ws + off); off += (size_t)3 * ND * NH * 2;   // 1.5 MB
  __bf16* p_ws = (__bf16*)(ws + off); off += (size_t)NROWS * NH * 2;    // 64 MB
  __bf16* k_ws = (__bf16*)(ws + off); off += (size_t)NROWS * NH * 2;    // 64 MB
  __bf16* vt_ws= (__bf16*)(ws + off); off += (size_t)NROWS * NH * 2;    // 64 MB (tiled)
  float*  L_ws = (float*)(ws + off);  off += (size_t)NROWS * 4;         // 0.25 MB

  prep_w<<<dim3(512), dim3(256), 0, stream>>>(Wq, Wk, Wv, wT);
  proj_kernel<<<dim3(1024), dim3(512), 0, stream>>>(x, wT, p_ws, k_ws, L_ws, vt_ws);
  attn_kernel<<<dim3(1024), dim3(512), 0, stream>>>(p_ws, k_ws, L_ws, vt_ws, out);
}